// Round 1
// baseline (32.882 us; speedup 1.0000x reference)
//
#include <hip/hip_runtime.h>
#include <math.h>

// LightweightConv1dTBC: out[t,b,c] = sum_k x[t-15+k, b, c] * softmax(w[h(c),:])[k] + bias[c]
// T=2048 B=8 C=1024 H=16 K=31 P=15, R = C/H = 64 channels per head.

#define T_DIM 2048
#define B_DIM 8
#define C_DIM 1024
#define H_DIM 16
#define K_DIM 31
#define P_PAD 15

#define T_TILE 128
#define C_TILE 64                       // == R, one head per block
#define NWAVE 4                         // 256 threads
#define STRIP (T_TILE / NWAVE)          // 32 outputs per thread
#define ROWS (T_TILE + K_DIM - 1)       // 158 staged rows (incl. halo)

__global__ __launch_bounds__(256, 4) void lwconv_tbc_kernel(
    const float* __restrict__ x,       // (T, B, C)
    const float* __restrict__ weight,  // (H, 1, K)
    const float* __restrict__ bias,    // (C,)
    float* __restrict__ out)           // (T, B, C)
{
    __shared__ float s_x[ROWS * C_TILE];
    __shared__ float s_w[K_DIM];

    const int cTile = blockIdx.x;      // 0..15
    const int b     = blockIdx.y;      // 0..7
    const int tTile = blockIdx.z;      // 0..15
    const int c0 = cTile * C_TILE;
    const int h  = cTile;              // C_TILE == R, so head index == cTile
    const int t0 = tTile * T_TILE;
    const int tid = threadIdx.x;

    // --- softmax of this head's 31 weights (serial on thread 0; trivial) ---
    if (tid == 0) {
        float wv[K_DIM];
        float m = -1e30f;
        for (int k = 0; k < K_DIM; ++k) {
            wv[k] = weight[h * K_DIM + k];
            m = fmaxf(m, wv[k]);
        }
        float s = 0.f;
        for (int k = 0; k < K_DIM; ++k) { wv[k] = expf(wv[k] - m); s += wv[k]; }
        const float inv = 1.f / s;
        for (int k = 0; k < K_DIM; ++k) s_w[k] = wv[k] * inv;
    }

    // --- stage x tile (ROWS x C_TILE) into LDS, zero-padded at T boundaries ---
    // float4 per slot: 16 slots per row, 2528 slots total.
    const int NV4 = ROWS * (C_TILE / 4);
    for (int idx = tid; idx < NV4; idx += 256) {
        const int row = idx >> 4;          // / 16
        const int c4  = idx & 15;
        const int t   = t0 - P_PAD + row;
        float4 v = make_float4(0.f, 0.f, 0.f, 0.f);
        if (t >= 0 && t < T_DIM) {
            v = *reinterpret_cast<const float4*>(
                    &x[((size_t)t * B_DIM + b) * C_DIM + c0 + c4 * 4]);
        }
        *reinterpret_cast<float4*>(&s_x[row * C_TILE + c4 * 4]) = v;
    }
    __syncthreads();

    // --- weights to registers (uniform across block) ---
    float w[K_DIM];
    #pragma unroll
    for (int k = 0; k < K_DIM; ++k) w[k] = s_w[k];

    const int lane  = tid & 63;        // channel within tile
    const int strip = tid >> 6;        // 0..3, which T-strip of 32
    const int c = c0 + lane;
    const float bv = bias[c];

    // --- register sliding window over T ---
    // LDS row r holds t = t0 - 15 + r. Output t = t0 + r0 + i needs rows
    // (r0+i) .. (r0+i+30).
    const int r0 = strip * STRIP;
    float win[K_DIM];
    #pragma unroll
    for (int k = 0; k < K_DIM; ++k) win[k] = s_x[(r0 + k) * C_TILE + lane];

    #pragma unroll
    for (int i = 0; i < STRIP; ++i) {
        float acc = bv;
        #pragma unroll
        for (int k = 0; k < K_DIM; ++k) acc = fmaf(win[k], w[k], acc);
        const int t = t0 + r0 + i;
        out[((size_t)t * B_DIM + b) * C_DIM + c] = acc;
        if (i < STRIP - 1) {
            #pragma unroll
            for (int k = 0; k < K_DIM - 1; ++k) win[k] = win[k + 1];
            win[K_DIM - 1] = s_x[(r0 + i + K_DIM) * C_TILE + lane];
        }
    }
}

extern "C" void kernel_launch(void* const* d_in, const int* in_sizes, int n_in,
                              void* d_out, int out_size, void* d_ws, size_t ws_size,
                              hipStream_t stream) {
    const float* x      = (const float*)d_in[0];
    const float* weight = (const float*)d_in[1];
    const float* bias   = (const float*)d_in[2];
    float* out = (float*)d_out;

    dim3 grid(C_DIM / C_TILE, B_DIM, T_DIM / T_TILE);   // (16, 8, 16) = 2048 blocks
    dim3 block(256);
    lwconv_tbc_kernel<<<grid, block, 0, stream>>>(x, weight, bias, out);
}